// Round 14
// baseline (417.933 us; speedup 1.0000x reference)
//
#include <hip/hip_runtime.h>

// ---------------------------------------------------------------------------
// SemanticMemoryLatentSpace, fully factored (see R7 header).
// R13: decoupled two-wave scan with MINIMAL COUPLING.
//   wave0: identical decision loop, but FLAG release only every 8 rounds
//          (8 lgkmcnt-drains total instead of 64); journal = RING only.
//   wave1: wakes 8 times (s_sleep(32) poll), processes 64 steps per burst.
//   Purpose: if R12's 346us was wave1-interference (polling drains, L1/LSU
//   contention), this removes it; if unchanged, wave0's floor is internal.
// Arithmetic op-identical to R8 -> same output.
// ---------------------------------------------------------------------------

#define A_BOOSTF 0.012247448713915891f // 1.5*alpha (growth==0 always)

template <int CTRL>
__device__ __forceinline__ float dpp_f(float x) {
  return __int_as_float(
      __builtin_amdgcn_mov_dpp(__float_as_int(x), CTRL, 0xf, 0xf, true));
}
template <int CTRL>
__device__ __forceinline__ unsigned dpp_u(unsigned x) {
  return (unsigned)__builtin_amdgcn_mov_dpp((int)x, CTRL, 0xf, 0xf, true);
}
__device__ __forceinline__ float rdlane_f(float x, int l) {
  return __int_as_float(__builtin_amdgcn_readlane(__float_as_int(x), l));
}
__device__ __forceinline__ unsigned rdlane_u(unsigned x, int l) {
  return (unsigned)__builtin_amdgcn_readlane((int)x, l);
}
__device__ __forceinline__ float wave_sum64(float v) {
  v += dpp_f<0xB1>(v);
  v += dpp_f<0x4E>(v);
  v += dpp_f<0x124>(v);
  v += dpp_f<0x128>(v);
  return (rdlane_f(v, 0) + rdlane_f(v, 16)) + (rdlane_f(v, 32) + rdlane_f(v, 48));
}
__device__ __forceinline__ unsigned sortable(float v) {
  unsigned u = __float_as_uint(v);
  return u ^ (unsigned)(((int)u >> 31) | 0x80000000);
}
__device__ __forceinline__ float unsortable(unsigned x) {
  unsigned u = (x & 0x80000000u) ? (x ^ 0x80000000u) : ~x;
  return __uint_as_float(u);
}
__device__ __forceinline__ unsigned wave_umax64(unsigned v) {
  v = max(v, dpp_u<0xB1>(v));
  v = max(v, dpp_u<0x4E>(v));
  v = max(v, dpp_u<0x124>(v));
  v = max(v, dpp_u<0x128>(v));
  return max(max(rdlane_u(v, 0), rdlane_u(v, 16)),
             max(rdlane_u(v, 32), rdlane_u(v, 48)));
}

// ---------------- generic 32x32-tile fp32 GEMMs -----------------------------
__global__ __launch_bounds__(256) void gemm_nt(const float* __restrict__ A,
                                               const float* __restrict__ B,
                                               float* __restrict__ C,
                                               int N, int K) {
  __shared__ float As[32][33];
  __shared__ float Bs[32][33];
  int bx = blockIdx.x, by = blockIdx.y;
  int tid = threadIdx.x;
  int tx = tid & 15, ty = tid >> 4;
  float a00 = 0.f, a01 = 0.f, a10 = 0.f, a11 = 0.f;
  for (int k0 = 0; k0 < K; k0 += 32) {
    for (int l = tid; l < 1024; l += 256) {
      int r = l >> 5, c = l & 31;
      As[r][c] = A[(by * 32 + r) * K + k0 + c];
      Bs[r][c] = B[(bx * 32 + r) * K + k0 + c];
    }
    __syncthreads();
#pragma unroll
    for (int k = 0; k < 32; ++k) {
      float x0 = As[2 * ty][k], x1 = As[2 * ty + 1][k];
      float y0 = Bs[2 * tx][k], y1 = Bs[2 * tx + 1][k];
      a00 += x0 * y0; a01 += x0 * y1; a10 += x1 * y0; a11 += x1 * y1;
    }
    __syncthreads();
  }
  int i = by * 32 + 2 * ty, jj = bx * 32 + 2 * tx;
  C[i * N + jj] = a00;           C[i * N + jj + 1] = a01;
  C[(i + 1) * N + jj] = a10;     C[(i + 1) * N + jj + 1] = a11;
}

__global__ __launch_bounds__(256) void gemm_nn(const float* __restrict__ A,
                                               const float* __restrict__ B,
                                               float* __restrict__ C,
                                               int N, int K) {
  __shared__ float As[32][33];
  __shared__ float Bs[32][33];
  int bx = blockIdx.x, by = blockIdx.y;
  int tid = threadIdx.x;
  int tx = tid & 15, ty = tid >> 4;
  float a00 = 0.f, a01 = 0.f, a10 = 0.f, a11 = 0.f;
  for (int k0 = 0; k0 < K; k0 += 32) {
    for (int l = tid; l < 1024; l += 256) {
      int r = l >> 5, c = l & 31;
      As[r][c] = A[(by * 32 + r) * K + k0 + c];
      Bs[r][c] = B[(k0 + r) * N + bx * 32 + c];
    }
    __syncthreads();
#pragma unroll
    for (int k = 0; k < 32; ++k) {
      float x0 = As[2 * ty][k], x1 = As[2 * ty + 1][k];
      float y0 = Bs[k][2 * tx], y1 = Bs[k][2 * tx + 1];
      a00 += x0 * y0; a01 += x0 * y1; a10 += x1 * y0; a11 += x1 * y1;
    }
    __syncthreads();
  }
  int i = by * 32 + 2 * ty, jj = bx * 32 + 2 * tx;
  C[i * N + jj] = a00;           C[i * N + jj + 1] = a01;
  C[(i + 1) * N + jj] = a10;     C[(i + 1) * N + jj + 1] = a11;
}

__global__ __launch_bounds__(256) void final_gemm(const float* __restrict__ G,
                                                  const float* __restrict__ E,
                                                  const float* __restrict__ M0,
                                                  const float* __restrict__ W,
                                                  const float* __restrict__ gS,
                                                  float* __restrict__ out) {
  __shared__ float As[32][33];
  __shared__ float Bs[32][33];
  int bx = blockIdx.x, by = blockIdx.y;
  int tid = threadIdx.x;
  int tx = tid & 15, ty = tid >> 4;
  float a00 = 0.f, a01 = 0.f, a10 = 0.f, a11 = 0.f;
  for (int k0 = 0; k0 < 512; k0 += 32) {
    for (int l = tid; l < 1024; l += 256) {
      int r = l >> 5, c = l & 31;
      As[r][c] = G[(by * 32 + r) * 512 + k0 + c] * W[k0 + c];
      Bs[r][c] = E[(k0 + r) * 384 + bx * 32 + c];
    }
    __syncthreads();
#pragma unroll
    for (int k = 0; k < 32; ++k) {
      float x0 = As[2 * ty][k], x1 = As[2 * ty + 1][k];
      float y0 = Bs[k][2 * tx], y1 = Bs[k][2 * tx + 1];
      a00 += x0 * y0; a01 += x0 * y1; a10 += x1 * y0; a11 += x1 * y1;
    }
    __syncthreads();
  }
  float gv = gS[0];
  int i = by * 32 + 2 * ty, jj = bx * 32 + 2 * tx;
  out[i * 384 + jj]         = gv * M0[i * 384 + jj]         + a00;
  out[i * 384 + jj + 1]     = gv * M0[i * 384 + jj + 1]     + a01;
  out[(i + 1) * 384 + jj]     = gv * M0[(i + 1) * 384 + jj]     + a10;
  out[(i + 1) * 384 + jj + 1] = gv * M0[(i + 1) * 384 + jj + 1] + a11;
}

__global__ __launch_bounds__(256) void prep_kernel(const float* __restrict__ E,
                                                   const float* __restrict__ M0,
                                                   const float* __restrict__ K0,
                                                   float* __restrict__ u,
                                                   float* __restrict__ Kpart) {
  __shared__ double wr[4];
  int b = blockIdx.x;
  int tid = threadIdx.x, lane = tid & 63, wv = tid >> 6;
  if (b < 128) {
    int row = b * 4 + wv;
    const float4* e4 = (const float4*)(E + row * 384);
    const float4* m4 = (const float4*)(M0 + row * 384);
    float p = 0.f;
    for (int i = lane; i < 96; i += 64) {
      float4 a = e4[i], bb = m4[i];
      p += a.x * bb.x + a.y * bb.y + a.z * bb.z + a.w * bb.w;
    }
#pragma unroll
    for (int off = 32; off; off >>= 1) p += __shfl_down(p, off);
    if (lane == 0) u[row] = p;
  } else {
    int cb = b - 128;
    const float* p = K0 + cb * 2304 + tid * 9;
    double acc = 0.0;
#pragma unroll
    for (int i = 0; i < 9; ++i) { double v = (double)p[i]; acc += v * v; }
#pragma unroll
    for (int off = 32; off; off >>= 1) acc += __shfl_down(acc, off);
    if (lane == 0) wr[wv] = acc;
    __syncthreads();
    if (tid == 0) Kpart[cb] = (float)(wr[0] + wr[1] + wr[2] + wr[3]);
  }
}

// ---------------- decoupled two-wave scan, minimal coupling -----------------
__global__ __launch_bounds__(128) void scan_kernel(const float* __restrict__ G,
                                                   const float* __restrict__ u,
                                                   const float* __restrict__ Kpart,
                                                   float* __restrict__ Wout,
                                                   float* __restrict__ gOut) {
  __shared__ float RAW[100 * 257];     // 102800 B, rows = clusters (<100)
  __shared__ float gx_tbl[512 * 8];    // [t][d]: d=0 -> G[t][t], d>=1 -> G[t][t+d]
  __shared__ float ren_tbl[512];       // rcp(sqrt(G[t][t]))
  __shared__ float u_sh[512];
  __shared__ float wh_sh[512];
  __shared__ float4 RING[512];         // full-depth ring {bnew, idxbits, nov, 0}
  __shared__ int FLAG;

  const int tid = threadIdx.x;
  const int wid = tid >> 6;
  const int lane = tid & 63;

  // ---- cooperative init ----
  float4 z4 = {0.f, 0.f, 0.f, 0.f};
  for (int i = tid; i < 6425; i += 128) ((float4*)RAW)[i] = z4;
  for (int tt = tid; tt < 512; tt += 128) {
    float trv = G[tt * 512 + tt];
    gx_tbl[tt * 8] = trv;
#pragma unroll
    for (int d = 1; d < 8; ++d)
      gx_tbl[tt * 8 + d] = (tt + d < 512) ? G[tt * 512 + tt + d] : 0.f;
    ren_tbl[tt] = __builtin_amdgcn_rcpf(__builtin_amdgcn_sqrtf(trv));
  }
  if (tid < 128) ((float4*)u_sh)[tid] = ((const float4*)u)[tid];
  if (tid == 0) FLAG = 0;
  __syncthreads();

  if (wid == 0) {
    // ================== WAVE 0: decision wave ==================
    float d0 = 1.f, d1 = 1.f, cn0 = 0.f, cn1 = 0.f, s0 = 0.f, s1 = 0.f;
    int nact = 0;
    float r0[8], r1[8];
#pragma unroll
    for (int j = 0; j < 8; ++j) { r0[j] = 0.f; r1[j] = 0.f; }

    float bufA[8][4], bufB[8][4];
#pragma unroll
    for (int k = 0; k < 8; ++k)
#pragma unroll
      for (int m = 0; m < 4; ++m)
        bufA[k][m] = G[k * 512 + m * 64 + lane];

#define W0_ROUND(R_, CUR, NXT)                                                 \
    {                                                                          \
      const int t = 8 * (R_);                                                  \
      const int c = t & 255;                                                   \
      const int tn = t + 8;                                                    \
      if (tn < 512) {                                                          \
        const int nb = tn & ~255;                                              \
        _Pragma("unroll") for (int k = 0; k < 8; ++k)                          \
          _Pragma("unroll") for (int m = 0; m < 4; ++m)                        \
            NXT[k][m] = G[(tn + k) * 512 + nb + m * 64 + lane];                \
      }                                                                        \
      if (t == 256) {                                                          \
        for (int i = lane; i < 6425; i += 64) ((float4*)RAW)[i] = z4;          \
        __builtin_amdgcn_sched_barrier(0);                                     \
        const float* Gb = G + 256;                                             \
        float A[4][4], Bv[4][4];                                               \
        float4 SA[4], SB[4];                                                   \
        _Pragma("unroll") for (int j = 0; j < 4; ++j) {                        \
          _Pragma("unroll") for (int m = 0; m < 4; ++m)                        \
            A[j][m] = Gb[j * 512 + m * 64 + lane];                             \
          SA[j] = RING[j];                                                     \
        }                                                                      \
        for (int s = 0; s < 256; s += 8) {                                     \
          _Pragma("unroll") for (int j = 0; j < 4; ++j) {                      \
            _Pragma("unroll") for (int m = 0; m < 4; ++m)                      \
              Bv[j][m] = Gb[(s + 4 + j) * 512 + m * 64 + lane];                \
            SB[j] = RING[s + 4 + j];                                           \
          }                                                                    \
          _Pragma("unroll") for (int j = 0; j < 4; ++j) {                      \
            float bh = SA[j].x; int id = __float_as_int(SA[j].y);              \
            _Pragma("unroll") for (int m = 0; m < 4; ++m)                      \
              atomicAdd(&RAW[id * 257 + m * 64 + lane], bh * A[j][m]);         \
          }                                                                    \
          if (s + 8 < 256) {                                                   \
            _Pragma("unroll") for (int j = 0; j < 4; ++j) {                    \
              _Pragma("unroll") for (int m = 0; m < 4; ++m)                    \
                A[j][m] = Gb[(s + 8 + j) * 512 + m * 64 + lane];               \
              SA[j] = RING[s + 8 + j];                                         \
            }                                                                  \
          }                                                                    \
          _Pragma("unroll") for (int j = 0; j < 4; ++j) {                      \
            float bh = SB[j].x; int id = __float_as_int(SB[j].y);              \
            _Pragma("unroll") for (int m = 0; m < 4; ++m)                      \
              atomicAdd(&RAW[id * 257 + m * 64 + lane], bh * Bv[j][m]);        \
          }                                                                    \
        }                                                                      \
        __builtin_amdgcn_sched_barrier(0);                                     \
        _Pragma("unroll") for (int j = 0; j < 8; ++j)                          \
          r0[j] = RAW[lane * 257 + j];                                         \
        if (lane < 36) {                                                       \
          _Pragma("unroll") for (int j = 0; j < 8; ++j)                        \
            r1[j] = RAW[(lane + 64) * 257 + j];                                \
        }                                                                      \
        __builtin_amdgcn_sched_barrier(0);                                     \
      }                                                                        \
      float trk[8], renk[8], gxv[8][8];                                        \
      _Pragma("unroll") for (int k = 0; k < 8; ++k) {                          \
        trk[k] = gx_tbl[(t + k) * 8];                                          \
        renk[k] = ren_tbl[t + k];                                              \
        _Pragma("unroll") for (int j = k + 1; j < 8; ++j)                      \
          gxv[k][j] = gx_tbl[(t + k) * 8 + (j - k)];                           \
      }                                                                        \
      float bnewA[8], novA[8];                                                 \
      int idxA[8];                                                             \
      _Pragma("unroll") for (int k = 0; k < 8; ++k) {                          \
        float v0 = (lane < nact) ? s0 * renk[k] * r0[k] : -2.f;                \
        float v1 = (lane + 64 < nact) ? s1 * renk[k] * r1[k] : -2.f;           \
        unsigned pk0 = (sortable(v0) & ~127u) | (unsigned)(127 - lane);        \
        unsigned pk1 = (sortable(v1) & ~127u) | (unsigned)(63 - lane);         \
        unsigned P = wave_umax64(max(pk0, pk1));                               \
        int imax = 127 - (int)(P & 127u);                                      \
        float M = unsortable(P & ~127u);                                       \
        float nov = (nact == 0) ? 1.f : fminf(1.f, fmaxf(0.f, 1.f - M * M));   \
        int create = (nov > 0.7f && nact < 100) ? 1 : 0;                       \
        const int idxs = create ? nact : imax;                                 \
        const int cl = idxs & 63, hi = idxs >> 6;                              \
        float dcA = create ? 1.f : 0.95f * d0;                                 \
        float dcB = create ? 1.f : 0.95f * d1;                                 \
        float ccA = create ? trk[k]                                            \
                           : (0.9025f * cn0 + 0.095f * (d0 * r0[k]) +          \
                              0.0025f * trk[k]);                               \
        float ccB = create ? trk[k]                                            \
                           : (0.9025f * cn1 + 0.095f * (d1 * r1[k]) +          \
                              0.0025f * trk[k]);                               \
        float scA = dcA * __builtin_amdgcn_rcpf(__builtin_amdgcn_sqrtf(ccA));  \
        float scB = dcB * __builtin_amdgcn_rcpf(__builtin_amdgcn_sqrtf(ccB));  \
        bool own0 = (lane == cl) && (hi == 0);                                 \
        bool own1 = (lane == cl) && (hi == 1);                                 \
        d0 = own0 ? dcA : d0; cn0 = own0 ? ccA : cn0; s0 = own0 ? scA : s0;    \
        d1 = own1 ? dcB : d1; cn1 = own1 ? ccB : cn1; s1 = own1 ? scB : s1;    \
        float bnew = create ? 1.f                                              \
                            : 0.05f * __builtin_amdgcn_rcpf(                   \
                                          rdlane_f(hi ? dcB : dcA, cl));       \
        nact += create;                                                        \
        float pb0 = own0 ? bnew : 0.f, pb1 = own1 ? bnew : 0.f;                \
        _Pragma("unroll") for (int j = k + 1; j < 8; ++j) {                    \
          r0[j] += pb0 * gxv[k][j];                                            \
          r1[j] += pb1 * gxv[k][j];                                            \
        }                                                                      \
        bnewA[k] = bnew; novA[k] = nov; idxA[k] = idxs;                        \
      }                                                                        \
      if (lane == 0) {                                                         \
        _Pragma("unroll") for (int k = 0; k < 8; ++k) {                        \
          float4 r4; r4.x = bnewA[k]; r4.y = __int_as_float(idxA[k]);          \
          r4.z = novA[k]; r4.w = 0.f;                                          \
          RING[t + k] = r4;                                                    \
        }                                                                      \
        if (((R_) & 7) == 7)                                                   \
          __hip_atomic_store(&FLAG, (R_) + 1, __ATOMIC_RELEASE,                \
                             __HIP_MEMORY_SCOPE_WORKGROUP);                    \
      }                                                                        \
      _Pragma("unroll") for (int k = 0; k < 8; ++k)                            \
        _Pragma("unroll") for (int m = 0; m < 4; ++m)                          \
          if (m * 64 + 63 >= c)                                                \
            atomicAdd(&RAW[idxA[k] * 257 + m * 64 + lane],                     \
                      bnewA[k] * CUR[k][m]);                                   \
      const int cnx = tn & 255;                                                \
      if (tn < 512 && cnx != 0) {                                              \
        _Pragma("unroll") for (int j = 0; j < 8; ++j)                          \
          r0[j] = RAW[lane * 257 + cnx + j];                                   \
        if (lane < 36) {                                                       \
          _Pragma("unroll") for (int j = 0; j < 8; ++j)                        \
            r1[j] = RAW[(lane + 64) * 257 + cnx + j];                          \
        }                                                                      \
      }                                                                        \
    }

    for (int R = 0; R < 64; R += 2) {
      W0_ROUND(R, bufA, bufB)
      W0_ROUND(R + 1, bufB, bufA)
    }
#undef W0_ROUND
  } else {
    // ================== WAVE 1: lag wave, 8 wake-ups ==================
    float q8[8];
#pragma unroll
    for (int gI = 0; gI < 8; ++gI) q8[gI] = 0.f;
    float n2 = wave_sum64(Kpart[lane]);
    float g = 1.f, ginv = 1.f;

    for (int chunk = 0; chunk < 8; ++chunk) {
      while (__hip_atomic_load(&FLAG, __ATOMIC_ACQUIRE,
                               __HIP_MEMORY_SCOPE_WORKGROUP) < (chunk + 1) * 8)
        __builtin_amdgcn_s_sleep(32);

      for (int r8 = 0; r8 < 8; ++r8) {
        const int R = chunk * 8 + r8;
        const int t = 8 * R;
        float B[8][8];
#pragma unroll
        for (int k = 0; k < 8; ++k)
#pragma unroll
          for (int gI = 0; gI < 8; ++gI)
            B[k][gI] = G[(t + k) * 512 + gI * 64 + lane];

        float4 rgv[8];
#pragma unroll
        for (int k = 0; k < 8; ++k) rgv[k] = RING[t + k];

        float trm[8], gxw[8][8];
#pragma unroll
        for (int m = 0; m < 8; ++m) {
          trm[m] = gx_tbl[(t + m) * 8];
#pragma unroll
          for (int j = m + 1; j < 8; ++j)
            gxw[m][j] = gx_tbl[(t + m) * 8 + (j - m)];
        }
        float4 uuA = *(const float4*)&u_sh[t];
        float4 uuB = *(const float4*)&u_sh[t + 4];
        float um[8] = {uuA.x, uuA.y, uuA.z, uuA.w, uuB.x, uuB.y, uuB.z, uuB.w};

        const int grp = t >> 6;
        float qsel = q8[0];
#pragma unroll
        for (int gI = 1; gI < 8; ++gI) qsel = (grp == gI) ? q8[gI] : qsel;
        float qeff[8];
#pragma unroll
        for (int k = 0; k < 8; ++k) qeff[k] = rdlane_f(qsel, (t & 63) + k);

        float wh[8];
#pragma unroll
        for (int m = 0; m < 8; ++m) {
          float nov = rgv[m].z;
          float iw = nov * __builtin_amdgcn_sqrtf(nov);
          float psc = 384.0f * __builtin_amdgcn_rcpf(fmaxf(trm[m], 1e-8f));
          float ccf = A_BOOSTF * iw * psc;
          float qv = g * (um[m] + qeff[m]);
          float n2n = n2 + 2.f * ccf * qv + ccf * ccf * trm[m] * trm[m];
          float kn = __builtin_amdgcn_sqrtf(n2n);
          float fct = (kn > 50.f) ? 50.f * __builtin_amdgcn_rcpf(kn) : 1.f;
          float fiv = (kn > 50.f) ? kn * 0.02f : 1.f;
          wh[m] = ccf * ginv;
          n2 = n2n * fct * fct; g *= fct; ginv *= fiv;
#pragma unroll
          for (int j = m + 1; j < 8; ++j)
            qeff[j] += wh[m] * gxw[m][j] * gxw[m][j];
        }

        if (lane == 0) {
#pragma unroll
          for (int m = 0; m < 8; ++m) wh_sh[t + m] = wh[m];
        }
#pragma unroll
        for (int gI = 0; gI < 8; ++gI)
#pragma unroll
          for (int k = 0; k < 8; ++k)
            q8[gI] += wh[k] * B[k][gI] * B[k][gI];
      }
    }

    for (int s2 = lane; s2 < 512; s2 += 64) Wout[s2] = wh_sh[s2] * g;
    if (lane == 0) gOut[0] = g;
  }
}

extern "C" void kernel_launch(void* const* d_in, const int* in_sizes, int n_in,
                              void* d_out, int out_size, void* d_ws,
                              size_t ws_size, hipStream_t stream) {
  const float* E = (const float*)d_in[0];   // [512,384]
  const float* K0 = (const float*)d_in[1];  // [384,384]
  float* out = (float*)d_out;               // [512,384]

  float* G = (float*)d_ws;                  // 512*512
  float* M0 = G + 512 * 512;                // 512*384
  float* u = M0 + 512 * 384;                // 512
  float* W = u + 512;                       // 512
  float* gS = W + 512;                      // 1
  float* Kpart = gS + 1;                    // 64

  gemm_nt<<<dim3(16, 16), 256, 0, stream>>>(E, E, G, 512, 384);     // G = E E^T
  gemm_nn<<<dim3(12, 16), 256, 0, stream>>>(E, K0, M0, 384, 384);   // M0 = E K0
  prep_kernel<<<192, 256, 0, stream>>>(E, M0, K0, u, Kpart);
  scan_kernel<<<1, 128, 0, stream>>>(G, u, Kpart, W, gS);
  final_gemm<<<dim3(12, 16), 256, 0, stream>>>(G, E, M0, W, gS, out);
}

// Round 15
// 366.870 us; speedup vs baseline: 1.1392x; 1.1392x over previous
//
#include <hip/hip_runtime.h>

// ---------------------------------------------------------------------------
// SemanticMemoryLatentSpace, fully factored (see R7 header).
// R14: ATOMIC-ELIMINATION A/B. Identical to R13 except the main loop's RAW
// updates use plain ds_read+add+ds_write RMW instead of atomicAdd (safe:
// each DS op's lanes hit distinct addresses; same-wave DS ops are in-order),
// issued inline per step so the DS pipe overlaps the VALU decision chain.
// The t=256 rebuild keeps atomics (unchanged) to isolate the variable.
// Bitwise-identical accumulation order -> same output.
// ---------------------------------------------------------------------------

#define A_BOOSTF 0.012247448713915891f // 1.5*alpha (growth==0 always)

template <int CTRL>
__device__ __forceinline__ float dpp_f(float x) {
  return __int_as_float(
      __builtin_amdgcn_mov_dpp(__float_as_int(x), CTRL, 0xf, 0xf, true));
}
template <int CTRL>
__device__ __forceinline__ unsigned dpp_u(unsigned x) {
  return (unsigned)__builtin_amdgcn_mov_dpp((int)x, CTRL, 0xf, 0xf, true);
}
__device__ __forceinline__ float rdlane_f(float x, int l) {
  return __int_as_float(__builtin_amdgcn_readlane(__float_as_int(x), l));
}
__device__ __forceinline__ unsigned rdlane_u(unsigned x, int l) {
  return (unsigned)__builtin_amdgcn_readlane((int)x, l);
}
__device__ __forceinline__ float wave_sum64(float v) {
  v += dpp_f<0xB1>(v);
  v += dpp_f<0x4E>(v);
  v += dpp_f<0x124>(v);
  v += dpp_f<0x128>(v);
  return (rdlane_f(v, 0) + rdlane_f(v, 16)) + (rdlane_f(v, 32) + rdlane_f(v, 48));
}
__device__ __forceinline__ unsigned sortable(float v) {
  unsigned u = __float_as_uint(v);
  return u ^ (unsigned)(((int)u >> 31) | 0x80000000);
}
__device__ __forceinline__ float unsortable(unsigned x) {
  unsigned u = (x & 0x80000000u) ? (x ^ 0x80000000u) : ~x;
  return __uint_as_float(u);
}
__device__ __forceinline__ unsigned wave_umax64(unsigned v) {
  v = max(v, dpp_u<0xB1>(v));
  v = max(v, dpp_u<0x4E>(v));
  v = max(v, dpp_u<0x124>(v));
  v = max(v, dpp_u<0x128>(v));
  return max(max(rdlane_u(v, 0), rdlane_u(v, 16)),
             max(rdlane_u(v, 32), rdlane_u(v, 48)));
}

// ---------------- generic 32x32-tile fp32 GEMMs -----------------------------
__global__ __launch_bounds__(256) void gemm_nt(const float* __restrict__ A,
                                               const float* __restrict__ B,
                                               float* __restrict__ C,
                                               int N, int K) {
  __shared__ float As[32][33];
  __shared__ float Bs[32][33];
  int bx = blockIdx.x, by = blockIdx.y;
  int tid = threadIdx.x;
  int tx = tid & 15, ty = tid >> 4;
  float a00 = 0.f, a01 = 0.f, a10 = 0.f, a11 = 0.f;
  for (int k0 = 0; k0 < K; k0 += 32) {
    for (int l = tid; l < 1024; l += 256) {
      int r = l >> 5, c = l & 31;
      As[r][c] = A[(by * 32 + r) * K + k0 + c];
      Bs[r][c] = B[(bx * 32 + r) * K + k0 + c];
    }
    __syncthreads();
#pragma unroll
    for (int k = 0; k < 32; ++k) {
      float x0 = As[2 * ty][k], x1 = As[2 * ty + 1][k];
      float y0 = Bs[2 * tx][k], y1 = Bs[2 * tx + 1][k];
      a00 += x0 * y0; a01 += x0 * y1; a10 += x1 * y0; a11 += x1 * y1;
    }
    __syncthreads();
  }
  int i = by * 32 + 2 * ty, jj = bx * 32 + 2 * tx;
  C[i * N + jj] = a00;           C[i * N + jj + 1] = a01;
  C[(i + 1) * N + jj] = a10;     C[(i + 1) * N + jj + 1] = a11;
}

__global__ __launch_bounds__(256) void gemm_nn(const float* __restrict__ A,
                                               const float* __restrict__ B,
                                               float* __restrict__ C,
                                               int N, int K) {
  __shared__ float As[32][33];
  __shared__ float Bs[32][33];
  int bx = blockIdx.x, by = blockIdx.y;
  int tid = threadIdx.x;
  int tx = tid & 15, ty = tid >> 4;
  float a00 = 0.f, a01 = 0.f, a10 = 0.f, a11 = 0.f;
  for (int k0 = 0; k0 < K; k0 += 32) {
    for (int l = tid; l < 1024; l += 256) {
      int r = l >> 5, c = l & 31;
      As[r][c] = A[(by * 32 + r) * K + k0 + c];
      Bs[r][c] = B[(k0 + r) * N + bx * 32 + c];
    }
    __syncthreads();
#pragma unroll
    for (int k = 0; k < 32; ++k) {
      float x0 = As[2 * ty][k], x1 = As[2 * ty + 1][k];
      float y0 = Bs[k][2 * tx], y1 = Bs[k][2 * tx + 1];
      a00 += x0 * y0; a01 += x0 * y1; a10 += x1 * y0; a11 += x1 * y1;
    }
    __syncthreads();
  }
  int i = by * 32 + 2 * ty, jj = bx * 32 + 2 * tx;
  C[i * N + jj] = a00;           C[i * N + jj + 1] = a01;
  C[(i + 1) * N + jj] = a10;     C[(i + 1) * N + jj + 1] = a11;
}

__global__ __launch_bounds__(256) void final_gemm(const float* __restrict__ G,
                                                  const float* __restrict__ E,
                                                  const float* __restrict__ M0,
                                                  const float* __restrict__ W,
                                                  const float* __restrict__ gS,
                                                  float* __restrict__ out) {
  __shared__ float As[32][33];
  __shared__ float Bs[32][33];
  int bx = blockIdx.x, by = blockIdx.y;
  int tid = threadIdx.x;
  int tx = tid & 15, ty = tid >> 4;
  float a00 = 0.f, a01 = 0.f, a10 = 0.f, a11 = 0.f;
  for (int k0 = 0; k0 < 512; k0 += 32) {
    for (int l = tid; l < 1024; l += 256) {
      int r = l >> 5, c = l & 31;
      As[r][c] = G[(by * 32 + r) * 512 + k0 + c] * W[k0 + c];
      Bs[r][c] = E[(k0 + r) * 384 + bx * 32 + c];
    }
    __syncthreads();
#pragma unroll
    for (int k = 0; k < 32; ++k) {
      float x0 = As[2 * ty][k], x1 = As[2 * ty + 1][k];
      float y0 = Bs[k][2 * tx], y1 = Bs[k][2 * tx + 1];
      a00 += x0 * y0; a01 += x0 * y1; a10 += x1 * y0; a11 += x1 * y1;
    }
    __syncthreads();
  }
  float gv = gS[0];
  int i = by * 32 + 2 * ty, jj = bx * 32 + 2 * tx;
  out[i * 384 + jj]         = gv * M0[i * 384 + jj]         + a00;
  out[i * 384 + jj + 1]     = gv * M0[i * 384 + jj + 1]     + a01;
  out[(i + 1) * 384 + jj]     = gv * M0[(i + 1) * 384 + jj]     + a10;
  out[(i + 1) * 384 + jj + 1] = gv * M0[(i + 1) * 384 + jj + 1] + a11;
}

__global__ __launch_bounds__(256) void prep_kernel(const float* __restrict__ E,
                                                   const float* __restrict__ M0,
                                                   const float* __restrict__ K0,
                                                   float* __restrict__ u,
                                                   float* __restrict__ Kpart) {
  __shared__ double wr[4];
  int b = blockIdx.x;
  int tid = threadIdx.x, lane = tid & 63, wv = tid >> 6;
  if (b < 128) {
    int row = b * 4 + wv;
    const float4* e4 = (const float4*)(E + row * 384);
    const float4* m4 = (const float4*)(M0 + row * 384);
    float p = 0.f;
    for (int i = lane; i < 96; i += 64) {
      float4 a = e4[i], bb = m4[i];
      p += a.x * bb.x + a.y * bb.y + a.z * bb.z + a.w * bb.w;
    }
#pragma unroll
    for (int off = 32; off; off >>= 1) p += __shfl_down(p, off);
    if (lane == 0) u[row] = p;
  } else {
    int cb = b - 128;
    const float* p = K0 + cb * 2304 + tid * 9;
    double acc = 0.0;
#pragma unroll
    for (int i = 0; i < 9; ++i) { double v = (double)p[i]; acc += v * v; }
#pragma unroll
    for (int off = 32; off; off >>= 1) acc += __shfl_down(acc, off);
    if (lane == 0) wr[wv] = acc;
    __syncthreads();
    if (tid == 0) Kpart[cb] = (float)(wr[0] + wr[1] + wr[2] + wr[3]);
  }
}

// ---------------- decoupled two-wave scan, plain-RMW main loop --------------
__global__ __launch_bounds__(128) void scan_kernel(const float* __restrict__ G,
                                                   const float* __restrict__ u,
                                                   const float* __restrict__ Kpart,
                                                   float* __restrict__ Wout,
                                                   float* __restrict__ gOut) {
  __shared__ float RAW[100 * 257];     // 102800 B, rows = clusters (<100)
  __shared__ float gx_tbl[512 * 8];    // [t][d]: d=0 -> G[t][t], d>=1 -> G[t][t+d]
  __shared__ float ren_tbl[512];       // rcp(sqrt(G[t][t]))
  __shared__ float u_sh[512];
  __shared__ float wh_sh[512];
  __shared__ float4 RING[512];         // full-depth ring {bnew, idxbits, nov, 0}
  __shared__ int FLAG;

  const int tid = threadIdx.x;
  const int wid = tid >> 6;
  const int lane = tid & 63;

  // ---- cooperative init ----
  float4 z4 = {0.f, 0.f, 0.f, 0.f};
  for (int i = tid; i < 6425; i += 128) ((float4*)RAW)[i] = z4;
  for (int tt = tid; tt < 512; tt += 128) {
    float trv = G[tt * 512 + tt];
    gx_tbl[tt * 8] = trv;
#pragma unroll
    for (int d = 1; d < 8; ++d)
      gx_tbl[tt * 8 + d] = (tt + d < 512) ? G[tt * 512 + tt + d] : 0.f;
    ren_tbl[tt] = __builtin_amdgcn_rcpf(__builtin_amdgcn_sqrtf(trv));
  }
  if (tid < 128) ((float4*)u_sh)[tid] = ((const float4*)u)[tid];
  if (tid == 0) FLAG = 0;
  __syncthreads();

  if (wid == 0) {
    // ================== WAVE 0: decision wave ==================
    float d0 = 1.f, d1 = 1.f, cn0 = 0.f, cn1 = 0.f, s0 = 0.f, s1 = 0.f;
    int nact = 0;
    float r0[8], r1[8];
#pragma unroll
    for (int j = 0; j < 8; ++j) { r0[j] = 0.f; r1[j] = 0.f; }

    float bufA[8][4], bufB[8][4];
#pragma unroll
    for (int k = 0; k < 8; ++k)
#pragma unroll
      for (int m = 0; m < 4; ++m)
        bufA[k][m] = G[k * 512 + m * 64 + lane];

#define W0_ROUND(R_, CUR, NXT)                                                 \
    {                                                                          \
      const int t = 8 * (R_);                                                  \
      const int c = t & 255;                                                   \
      const int tn = t + 8;                                                    \
      if (tn < 512) {                                                          \
        const int nb = tn & ~255;                                              \
        _Pragma("unroll") for (int k = 0; k < 8; ++k)                          \
          _Pragma("unroll") for (int m = 0; m < 4; ++m)                        \
            NXT[k][m] = G[(tn + k) * 512 + nb + m * 64 + lane];                \
      }                                                                        \
      if (t == 256) {                                                          \
        for (int i = lane; i < 6425; i += 64) ((float4*)RAW)[i] = z4;          \
        __builtin_amdgcn_sched_barrier(0);                                     \
        const float* Gb = G + 256;                                             \
        float A[4][4], Bv[4][4];                                               \
        float4 SA[4], SB[4];                                                   \
        _Pragma("unroll") for (int j = 0; j < 4; ++j) {                        \
          _Pragma("unroll") for (int m = 0; m < 4; ++m)                        \
            A[j][m] = Gb[j * 512 + m * 64 + lane];                             \
          SA[j] = RING[j];                                                     \
        }                                                                      \
        for (int s = 0; s < 256; s += 8) {                                     \
          _Pragma("unroll") for (int j = 0; j < 4; ++j) {                      \
            _Pragma("unroll") for (int m = 0; m < 4; ++m)                      \
              Bv[j][m] = Gb[(s + 4 + j) * 512 + m * 64 + lane];                \
            SB[j] = RING[s + 4 + j];                                           \
          }                                                                    \
          _Pragma("unroll") for (int j = 0; j < 4; ++j) {                      \
            float bh = SA[j].x; int id = __float_as_int(SA[j].y);              \
            _Pragma("unroll") for (int m = 0; m < 4; ++m)                      \
              atomicAdd(&RAW[id * 257 + m * 64 + lane], bh * A[j][m]);         \
          }                                                                    \
          if (s + 8 < 256) {                                                   \
            _Pragma("unroll") for (int j = 0; j < 4; ++j) {                    \
              _Pragma("unroll") for (int m = 0; m < 4; ++m)                    \
                A[j][m] = Gb[(s + 8 + j) * 512 + m * 64 + lane];               \
              SA[j] = RING[s + 8 + j];                                         \
            }                                                                  \
          }                                                                    \
          _Pragma("unroll") for (int j = 0; j < 4; ++j) {                      \
            float bh = SB[j].x; int id = __float_as_int(SB[j].y);              \
            _Pragma("unroll") for (int m = 0; m < 4; ++m)                      \
              atomicAdd(&RAW[id * 257 + m * 64 + lane], bh * Bv[j][m]);        \
          }                                                                    \
        }                                                                      \
        __builtin_amdgcn_sched_barrier(0);                                     \
        _Pragma("unroll") for (int j = 0; j < 8; ++j)                          \
          r0[j] = RAW[lane * 257 + j];                                         \
        if (lane < 36) {                                                       \
          _Pragma("unroll") for (int j = 0; j < 8; ++j)                        \
            r1[j] = RAW[(lane + 64) * 257 + j];                                \
        }                                                                      \
        __builtin_amdgcn_sched_barrier(0);                                     \
      }                                                                        \
      float trk[8], renk[8], gxv[8][8];                                        \
      _Pragma("unroll") for (int k = 0; k < 8; ++k) {                          \
        trk[k] = gx_tbl[(t + k) * 8];                                          \
        renk[k] = ren_tbl[t + k];                                              \
        _Pragma("unroll") for (int j = k + 1; j < 8; ++j)                      \
          gxv[k][j] = gx_tbl[(t + k) * 8 + (j - k)];                           \
      }                                                                        \
      float bnewA[8], novA[8];                                                 \
      int idxA[8];                                                             \
      _Pragma("unroll") for (int k = 0; k < 8; ++k) {                          \
        float v0 = (lane < nact) ? s0 * renk[k] * r0[k] : -2.f;                \
        float v1 = (lane + 64 < nact) ? s1 * renk[k] * r1[k] : -2.f;           \
        unsigned pk0 = (sortable(v0) & ~127u) | (unsigned)(127 - lane);        \
        unsigned pk1 = (sortable(v1) & ~127u) | (unsigned)(63 - lane);         \
        unsigned P = wave_umax64(max(pk0, pk1));                               \
        int imax = 127 - (int)(P & 127u);                                      \
        float M = unsortable(P & ~127u);                                       \
        float nov = (nact == 0) ? 1.f : fminf(1.f, fmaxf(0.f, 1.f - M * M));   \
        int create = (nov > 0.7f && nact < 100) ? 1 : 0;                       \
        const int idxs = create ? nact : imax;                                 \
        const int cl = idxs & 63, hi = idxs >> 6;                              \
        float dcA = create ? 1.f : 0.95f * d0;                                 \
        float dcB = create ? 1.f : 0.95f * d1;                                 \
        float ccA = create ? trk[k]                                            \
                           : (0.9025f * cn0 + 0.095f * (d0 * r0[k]) +          \
                              0.0025f * trk[k]);                               \
        float ccB = create ? trk[k]                                            \
                           : (0.9025f * cn1 + 0.095f * (d1 * r1[k]) +          \
                              0.0025f * trk[k]);                               \
        float scA = dcA * __builtin_amdgcn_rcpf(__builtin_amdgcn_sqrtf(ccA));  \
        float scB = dcB * __builtin_amdgcn_rcpf(__builtin_amdgcn_sqrtf(ccB));  \
        bool own0 = (lane == cl) && (hi == 0);                                 \
        bool own1 = (lane == cl) && (hi == 1);                                 \
        d0 = own0 ? dcA : d0; cn0 = own0 ? ccA : cn0; s0 = own0 ? scA : s0;    \
        d1 = own1 ? dcB : d1; cn1 = own1 ? ccB : cn1; s1 = own1 ? scB : s1;    \
        float bnew = create ? 1.f                                              \
                            : 0.05f * __builtin_amdgcn_rcpf(                   \
                                          rdlane_f(hi ? dcB : dcA, cl));       \
        nact += create;                                                        \
        float pb0 = own0 ? bnew : 0.f, pb1 = own1 ? bnew : 0.f;                \
        _Pragma("unroll") for (int j = k + 1; j < 8; ++j) {                    \
          r0[j] += pb0 * gxv[k][j];                                            \
          r1[j] += pb1 * gxv[k][j];                                            \
        }                                                                      \
        bnewA[k] = bnew; novA[k] = nov; idxA[k] = idxs;                        \
        /* plain RMW update (was atomicAdd): lanes hit distinct addrs, */      \
        /* same-wave DS ops are in-order -> race-free, same acc order. */      \
        _Pragma("unroll") for (int m = 0; m < 4; ++m)                          \
          if (m * 64 + 63 >= c) {                                              \
            const int a_ = idxs * 257 + m * 64 + lane;                         \
            RAW[a_] += bnew * CUR[k][m];                                       \
          }                                                                    \
      }                                                                        \
      if (lane == 0) {                                                         \
        _Pragma("unroll") for (int k = 0; k < 8; ++k) {                        \
          float4 r4; r4.x = bnewA[k]; r4.y = __int_as_float(idxA[k]);          \
          r4.z = novA[k]; r4.w = 0.f;                                          \
          RING[t + k] = r4;                                                    \
        }                                                                      \
        if (((R_) & 7) == 7)                                                   \
          __hip_atomic_store(&FLAG, (R_) + 1, __ATOMIC_RELEASE,                \
                             __HIP_MEMORY_SCOPE_WORKGROUP);                    \
      }                                                                        \
      const int cnx = tn & 255;                                                \
      if (tn < 512 && cnx != 0) {                                              \
        _Pragma("unroll") for (int j = 0; j < 8; ++j)                          \
          r0[j] = RAW[lane * 257 + cnx + j];                                   \
        if (lane < 36) {                                                       \
          _Pragma("unroll") for (int j = 0; j < 8; ++j)                        \
            r1[j] = RAW[(lane + 64) * 257 + cnx + j];                          \
        }                                                                      \
      }                                                                        \
    }

    for (int R = 0; R < 64; R += 2) {
      W0_ROUND(R, bufA, bufB)
      W0_ROUND(R + 1, bufB, bufA)
    }
#undef W0_ROUND
  } else {
    // ================== WAVE 1: lag wave, 8 wake-ups ==================
    float q8[8];
#pragma unroll
    for (int gI = 0; gI < 8; ++gI) q8[gI] = 0.f;
    float n2 = wave_sum64(Kpart[lane]);
    float g = 1.f, ginv = 1.f;

    for (int chunk = 0; chunk < 8; ++chunk) {
      while (__hip_atomic_load(&FLAG, __ATOMIC_ACQUIRE,
                               __HIP_MEMORY_SCOPE_WORKGROUP) < (chunk + 1) * 8)
        __builtin_amdgcn_s_sleep(32);

      for (int r8 = 0; r8 < 8; ++r8) {
        const int R = chunk * 8 + r8;
        const int t = 8 * R;
        float B[8][8];
#pragma unroll
        for (int k = 0; k < 8; ++k)
#pragma unroll
          for (int gI = 0; gI < 8; ++gI)
            B[k][gI] = G[(t + k) * 512 + gI * 64 + lane];

        float4 rgv[8];
#pragma unroll
        for (int k = 0; k < 8; ++k) rgv[k] = RING[t + k];

        float trm[8], gxw[8][8];
#pragma unroll
        for (int m = 0; m < 8; ++m) {
          trm[m] = gx_tbl[(t + m) * 8];
#pragma unroll
          for (int j = m + 1; j < 8; ++j)
            gxw[m][j] = gx_tbl[(t + m) * 8 + (j - m)];
        }
        float4 uuA = *(const float4*)&u_sh[t];
        float4 uuB = *(const float4*)&u_sh[t + 4];
        float um[8] = {uuA.x, uuA.y, uuA.z, uuA.w, uuB.x, uuB.y, uuB.z, uuB.w};

        const int grp = t >> 6;
        float qsel = q8[0];
#pragma unroll
        for (int gI = 1; gI < 8; ++gI) qsel = (grp == gI) ? q8[gI] : qsel;
        float qeff[8];
#pragma unroll
        for (int k = 0; k < 8; ++k) qeff[k] = rdlane_f(qsel, (t & 63) + k);

        float wh[8];
#pragma unroll
        for (int m = 0; m < 8; ++m) {
          float nov = rgv[m].z;
          float iw = nov * __builtin_amdgcn_sqrtf(nov);
          float psc = 384.0f * __builtin_amdgcn_rcpf(fmaxf(trm[m], 1e-8f));
          float ccf = A_BOOSTF * iw * psc;
          float qv = g * (um[m] + qeff[m]);
          float n2n = n2 + 2.f * ccf * qv + ccf * ccf * trm[m] * trm[m];
          float kn = __builtin_amdgcn_sqrtf(n2n);
          float fct = (kn > 50.f) ? 50.f * __builtin_amdgcn_rcpf(kn) : 1.f;
          float fiv = (kn > 50.f) ? kn * 0.02f : 1.f;
          wh[m] = ccf * ginv;
          n2 = n2n * fct * fct; g *= fct; ginv *= fiv;
#pragma unroll
          for (int j = m + 1; j < 8; ++j)
            qeff[j] += wh[m] * gxw[m][j] * gxw[m][j];
        }

        if (lane == 0) {
#pragma unroll
          for (int m = 0; m < 8; ++m) wh_sh[t + m] = wh[m];
        }
#pragma unroll
        for (int gI = 0; gI < 8; ++gI)
#pragma unroll
          for (int k = 0; k < 8; ++k)
            q8[gI] += wh[k] * B[k][gI] * B[k][gI];
      }
    }

    for (int s2 = lane; s2 < 512; s2 += 64) Wout[s2] = wh_sh[s2] * g;
    if (lane == 0) gOut[0] = g;
  }
}

extern "C" void kernel_launch(void* const* d_in, const int* in_sizes, int n_in,
                              void* d_out, int out_size, void* d_ws,
                              size_t ws_size, hipStream_t stream) {
  const float* E = (const float*)d_in[0];   // [512,384]
  const float* K0 = (const float*)d_in[1];  // [384,384]
  float* out = (float*)d_out;               // [512,384]

  float* G = (float*)d_ws;                  // 512*512
  float* M0 = G + 512 * 512;                // 512*384
  float* u = M0 + 512 * 384;                // 512
  float* W = u + 512;                       // 512
  float* gS = W + 512;                      // 1
  float* Kpart = gS + 1;                    // 64

  gemm_nt<<<dim3(16, 16), 256, 0, stream>>>(E, E, G, 512, 384);     // G = E E^T
  gemm_nn<<<dim3(12, 16), 256, 0, stream>>>(E, K0, M0, 384, 384);   // M0 = E K0
  prep_kernel<<<192, 256, 0, stream>>>(E, M0, K0, u, Kpart);
  scan_kernel<<<1, 128, 0, stream>>>(G, u, Kpart, W, gS);
  final_gemm<<<dim3(12, 16), 256, 0, stream>>>(G, E, M0, W, gS, out);
}

// Round 16
// 301.825 us; speedup vs baseline: 1.3847x; 1.2155x over previous
//
#include <hip/hip_runtime.h>

// ---------------------------------------------------------------------------
// SemanticMemoryLatentSpace, fully factored (see R7 header).
// R15: bank the atomic->RMW lever everywhere + chain micro-trims.
//   1) t=256 rebuild: atomicAdd -> plain RMW (same-wave DS in-order => safe
//      even for repeated rows; bitwise-same accumulation order).
//   2) gx_tbl consumed as float4 pairs (16 b128 reads/round vs 36 scalar).
//   3) bnew = rdlane(precomputed 0.05*rcp(dc)) — rcp off the serial chain.
// Output identical to R14.
// ---------------------------------------------------------------------------

#define A_BOOSTF 0.012247448713915891f // 1.5*alpha (growth==0 always)

template <int CTRL>
__device__ __forceinline__ float dpp_f(float x) {
  return __int_as_float(
      __builtin_amdgcn_mov_dpp(__float_as_int(x), CTRL, 0xf, 0xf, true));
}
template <int CTRL>
__device__ __forceinline__ unsigned dpp_u(unsigned x) {
  return (unsigned)__builtin_amdgcn_mov_dpp((int)x, CTRL, 0xf, 0xf, true);
}
__device__ __forceinline__ float rdlane_f(float x, int l) {
  return __int_as_float(__builtin_amdgcn_readlane(__float_as_int(x), l));
}
__device__ __forceinline__ unsigned rdlane_u(unsigned x, int l) {
  return (unsigned)__builtin_amdgcn_readlane((int)x, l);
}
__device__ __forceinline__ float wave_sum64(float v) {
  v += dpp_f<0xB1>(v);
  v += dpp_f<0x4E>(v);
  v += dpp_f<0x124>(v);
  v += dpp_f<0x128>(v);
  return (rdlane_f(v, 0) + rdlane_f(v, 16)) + (rdlane_f(v, 32) + rdlane_f(v, 48));
}
__device__ __forceinline__ unsigned sortable(float v) {
  unsigned u = __float_as_uint(v);
  return u ^ (unsigned)(((int)u >> 31) | 0x80000000);
}
__device__ __forceinline__ float unsortable(unsigned x) {
  unsigned u = (x & 0x80000000u) ? (x ^ 0x80000000u) : ~x;
  return __uint_as_float(u);
}
__device__ __forceinline__ unsigned wave_umax64(unsigned v) {
  v = max(v, dpp_u<0xB1>(v));
  v = max(v, dpp_u<0x4E>(v));
  v = max(v, dpp_u<0x124>(v));
  v = max(v, dpp_u<0x128>(v));
  return max(max(rdlane_u(v, 0), rdlane_u(v, 16)),
             max(rdlane_u(v, 32), rdlane_u(v, 48)));
}

// ---------------- generic 32x32-tile fp32 GEMMs -----------------------------
__global__ __launch_bounds__(256) void gemm_nt(const float* __restrict__ A,
                                               const float* __restrict__ B,
                                               float* __restrict__ C,
                                               int N, int K) {
  __shared__ float As[32][33];
  __shared__ float Bs[32][33];
  int bx = blockIdx.x, by = blockIdx.y;
  int tid = threadIdx.x;
  int tx = tid & 15, ty = tid >> 4;
  float a00 = 0.f, a01 = 0.f, a10 = 0.f, a11 = 0.f;
  for (int k0 = 0; k0 < K; k0 += 32) {
    for (int l = tid; l < 1024; l += 256) {
      int r = l >> 5, c = l & 31;
      As[r][c] = A[(by * 32 + r) * K + k0 + c];
      Bs[r][c] = B[(bx * 32 + r) * K + k0 + c];
    }
    __syncthreads();
#pragma unroll
    for (int k = 0; k < 32; ++k) {
      float x0 = As[2 * ty][k], x1 = As[2 * ty + 1][k];
      float y0 = Bs[2 * tx][k], y1 = Bs[2 * tx + 1][k];
      a00 += x0 * y0; a01 += x0 * y1; a10 += x1 * y0; a11 += x1 * y1;
    }
    __syncthreads();
  }
  int i = by * 32 + 2 * ty, jj = bx * 32 + 2 * tx;
  C[i * N + jj] = a00;           C[i * N + jj + 1] = a01;
  C[(i + 1) * N + jj] = a10;     C[(i + 1) * N + jj + 1] = a11;
}

__global__ __launch_bounds__(256) void gemm_nn(const float* __restrict__ A,
                                               const float* __restrict__ B,
                                               float* __restrict__ C,
                                               int N, int K) {
  __shared__ float As[32][33];
  __shared__ float Bs[32][33];
  int bx = blockIdx.x, by = blockIdx.y;
  int tid = threadIdx.x;
  int tx = tid & 15, ty = tid >> 4;
  float a00 = 0.f, a01 = 0.f, a10 = 0.f, a11 = 0.f;
  for (int k0 = 0; k0 < K; k0 += 32) {
    for (int l = tid; l < 1024; l += 256) {
      int r = l >> 5, c = l & 31;
      As[r][c] = A[(by * 32 + r) * K + k0 + c];
      Bs[r][c] = B[(k0 + r) * N + bx * 32 + c];
    }
    __syncthreads();
#pragma unroll
    for (int k = 0; k < 32; ++k) {
      float x0 = As[2 * ty][k], x1 = As[2 * ty + 1][k];
      float y0 = Bs[k][2 * tx], y1 = Bs[k][2 * tx + 1];
      a00 += x0 * y0; a01 += x0 * y1; a10 += x1 * y0; a11 += x1 * y1;
    }
    __syncthreads();
  }
  int i = by * 32 + 2 * ty, jj = bx * 32 + 2 * tx;
  C[i * N + jj] = a00;           C[i * N + jj + 1] = a01;
  C[(i + 1) * N + jj] = a10;     C[(i + 1) * N + jj + 1] = a11;
}

__global__ __launch_bounds__(256) void final_gemm(const float* __restrict__ G,
                                                  const float* __restrict__ E,
                                                  const float* __restrict__ M0,
                                                  const float* __restrict__ W,
                                                  const float* __restrict__ gS,
                                                  float* __restrict__ out) {
  __shared__ float As[32][33];
  __shared__ float Bs[32][33];
  int bx = blockIdx.x, by = blockIdx.y;
  int tid = threadIdx.x;
  int tx = tid & 15, ty = tid >> 4;
  float a00 = 0.f, a01 = 0.f, a10 = 0.f, a11 = 0.f;
  for (int k0 = 0; k0 < 512; k0 += 32) {
    for (int l = tid; l < 1024; l += 256) {
      int r = l >> 5, c = l & 31;
      As[r][c] = G[(by * 32 + r) * 512 + k0 + c] * W[k0 + c];
      Bs[r][c] = E[(k0 + r) * 384 + bx * 32 + c];
    }
    __syncthreads();
#pragma unroll
    for (int k = 0; k < 32; ++k) {
      float x0 = As[2 * ty][k], x1 = As[2 * ty + 1][k];
      float y0 = Bs[k][2 * tx], y1 = Bs[k][2 * tx + 1];
      a00 += x0 * y0; a01 += x0 * y1; a10 += x1 * y0; a11 += x1 * y1;
    }
    __syncthreads();
  }
  float gv = gS[0];
  int i = by * 32 + 2 * ty, jj = bx * 32 + 2 * tx;
  out[i * 384 + jj]         = gv * M0[i * 384 + jj]         + a00;
  out[i * 384 + jj + 1]     = gv * M0[i * 384 + jj + 1]     + a01;
  out[(i + 1) * 384 + jj]     = gv * M0[(i + 1) * 384 + jj]     + a10;
  out[(i + 1) * 384 + jj + 1] = gv * M0[(i + 1) * 384 + jj + 1] + a11;
}

__global__ __launch_bounds__(256) void prep_kernel(const float* __restrict__ E,
                                                   const float* __restrict__ M0,
                                                   const float* __restrict__ K0,
                                                   float* __restrict__ u,
                                                   float* __restrict__ Kpart) {
  __shared__ double wr[4];
  int b = blockIdx.x;
  int tid = threadIdx.x, lane = tid & 63, wv = tid >> 6;
  if (b < 128) {
    int row = b * 4 + wv;
    const float4* e4 = (const float4*)(E + row * 384);
    const float4* m4 = (const float4*)(M0 + row * 384);
    float p = 0.f;
    for (int i = lane; i < 96; i += 64) {
      float4 a = e4[i], bb = m4[i];
      p += a.x * bb.x + a.y * bb.y + a.z * bb.z + a.w * bb.w;
    }
#pragma unroll
    for (int off = 32; off; off >>= 1) p += __shfl_down(p, off);
    if (lane == 0) u[row] = p;
  } else {
    int cb = b - 128;
    const float* p = K0 + cb * 2304 + tid * 9;
    double acc = 0.0;
#pragma unroll
    for (int i = 0; i < 9; ++i) { double v = (double)p[i]; acc += v * v; }
#pragma unroll
    for (int off = 32; off; off >>= 1) acc += __shfl_down(acc, off);
    if (lane == 0) wr[wv] = acc;
    __syncthreads();
    if (tid == 0) Kpart[cb] = (float)(wr[0] + wr[1] + wr[2] + wr[3]);
  }
}

// ---------------- decoupled two-wave scan, all-RMW --------------------------
__global__ __launch_bounds__(128) void scan_kernel(const float* __restrict__ G,
                                                   const float* __restrict__ u,
                                                   const float* __restrict__ Kpart,
                                                   float* __restrict__ Wout,
                                                   float* __restrict__ gOut) {
  __shared__ float RAW[100 * 257];     // 102800 B, rows = clusters (<100)
  __shared__ float gx_tbl[512 * 8];    // [t][d]: d=0 -> G[t][t], d>=1 -> G[t][t+d]
  __shared__ float ren_tbl[512];       // rcp(sqrt(G[t][t]))
  __shared__ float u_sh[512];
  __shared__ float wh_sh[512];
  __shared__ float4 RING[512];         // full-depth ring {bnew, idxbits, nov, 0}
  __shared__ int FLAG;

  const int tid = threadIdx.x;
  const int wid = tid >> 6;
  const int lane = tid & 63;

  // ---- cooperative init ----
  float4 z4 = {0.f, 0.f, 0.f, 0.f};
  for (int i = tid; i < 6425; i += 128) ((float4*)RAW)[i] = z4;
  for (int tt = tid; tt < 512; tt += 128) {
    float trv = G[tt * 512 + tt];
    gx_tbl[tt * 8] = trv;
#pragma unroll
    for (int d = 1; d < 8; ++d)
      gx_tbl[tt * 8 + d] = (tt + d < 512) ? G[tt * 512 + tt + d] : 0.f;
    ren_tbl[tt] = __builtin_amdgcn_rcpf(__builtin_amdgcn_sqrtf(trv));
  }
  if (tid < 128) ((float4*)u_sh)[tid] = ((const float4*)u)[tid];
  if (tid == 0) FLAG = 0;
  __syncthreads();

  if (wid == 0) {
    // ================== WAVE 0: decision wave ==================
    float d0 = 1.f, d1 = 1.f, cn0 = 0.f, cn1 = 0.f, s0 = 0.f, s1 = 0.f;
    int nact = 0;
    float r0[8], r1[8];
#pragma unroll
    for (int j = 0; j < 8; ++j) { r0[j] = 0.f; r1[j] = 0.f; }

    float bufA[8][4], bufB[8][4];
#pragma unroll
    for (int k = 0; k < 8; ++k)
#pragma unroll
      for (int m = 0; m < 4; ++m)
        bufA[k][m] = G[k * 512 + m * 64 + lane];

    const float4* gx4 = (const float4*)gx_tbl;

#define W0_ROUND(R_, CUR, NXT)                                                 \
    {                                                                          \
      const int t = 8 * (R_);                                                  \
      const int c = t & 255;                                                   \
      const int tn = t + 8;                                                    \
      if (tn < 512) {                                                          \
        const int nb = tn & ~255;                                              \
        _Pragma("unroll") for (int k = 0; k < 8; ++k)                          \
          _Pragma("unroll") for (int m = 0; m < 4; ++m)                        \
            NXT[k][m] = G[(tn + k) * 512 + nb + m * 64 + lane];                \
      }                                                                        \
      if (t == 256) {                                                          \
        for (int i = lane; i < 6425; i += 64) ((float4*)RAW)[i] = z4;          \
        __builtin_amdgcn_sched_barrier(0);                                     \
        const float* Gb = G + 256;                                             \
        float A[4][4], Bv[4][4];                                               \
        float4 SA[4], SB[4];                                                   \
        _Pragma("unroll") for (int j = 0; j < 4; ++j) {                        \
          _Pragma("unroll") for (int m = 0; m < 4; ++m)                        \
            A[j][m] = Gb[j * 512 + m * 64 + lane];                             \
          SA[j] = RING[j];                                                     \
        }                                                                      \
        for (int s = 0; s < 256; s += 8) {                                     \
          _Pragma("unroll") for (int j = 0; j < 4; ++j) {                      \
            _Pragma("unroll") for (int m = 0; m < 4; ++m)                      \
              Bv[j][m] = Gb[(s + 4 + j) * 512 + m * 64 + lane];                \
            SB[j] = RING[s + 4 + j];                                           \
          }                                                                    \
          _Pragma("unroll") for (int j = 0; j < 4; ++j) {                      \
            float bh = SA[j].x; int id = __float_as_int(SA[j].y);              \
            _Pragma("unroll") for (int m = 0; m < 4; ++m) {                    \
              const int a_ = id * 257 + m * 64 + lane;                         \
              RAW[a_] += bh * A[j][m];                                         \
            }                                                                  \
          }                                                                    \
          if (s + 8 < 256) {                                                   \
            _Pragma("unroll") for (int j = 0; j < 4; ++j) {                    \
              _Pragma("unroll") for (int m = 0; m < 4; ++m)                    \
                A[j][m] = Gb[(s + 8 + j) * 512 + m * 64 + lane];               \
              SA[j] = RING[s + 8 + j];                                         \
            }                                                                  \
          }                                                                    \
          _Pragma("unroll") for (int j = 0; j < 4; ++j) {                      \
            float bh = SB[j].x; int id = __float_as_int(SB[j].y);              \
            _Pragma("unroll") for (int m = 0; m < 4; ++m) {                    \
              const int a_ = id * 257 + m * 64 + lane;                         \
              RAW[a_] += bh * Bv[j][m];                                        \
            }                                                                  \
          }                                                                    \
        }                                                                      \
        __builtin_amdgcn_sched_barrier(0);                                     \
        _Pragma("unroll") for (int j = 0; j < 8; ++j)                          \
          r0[j] = RAW[lane * 257 + j];                                         \
        if (lane < 36) {                                                       \
          _Pragma("unroll") for (int j = 0; j < 8; ++j)                        \
            r1[j] = RAW[(lane + 64) * 257 + j];                                \
        }                                                                      \
        __builtin_amdgcn_sched_barrier(0);                                     \
      }                                                                        \
      float trk[8], renk[8], gxv[8][8];                                        \
      _Pragma("unroll") for (int k = 0; k < 8; ++k) {                          \
        float4 lo = gx4[(t + k) * 2];                                          \
        float4 hi4 = gx4[(t + k) * 2 + 1];                                     \
        trk[k] = lo.x;                                                         \
        renk[k] = ren_tbl[t + k];                                              \
        _Pragma("unroll") for (int j = k + 1; j < 8; ++j) {                    \
          const int d_ = j - k;                                                \
          gxv[k][j] = (d_ == 1) ? lo.y : (d_ == 2) ? lo.z : (d_ == 3) ? lo.w   \
                      : (d_ == 4) ? hi4.x : (d_ == 5) ? hi4.y                  \
                      : (d_ == 6) ? hi4.z : hi4.w;                             \
        }                                                                      \
      }                                                                        \
      float bnewA[8], novA[8];                                                 \
      int idxA[8];                                                             \
      _Pragma("unroll") for (int k = 0; k < 8; ++k) {                          \
        float v0 = (lane < nact) ? s0 * renk[k] * r0[k] : -2.f;                \
        float v1 = (lane + 64 < nact) ? s1 * renk[k] * r1[k] : -2.f;           \
        unsigned pk0 = (sortable(v0) & ~127u) | (unsigned)(127 - lane);        \
        unsigned pk1 = (sortable(v1) & ~127u) | (unsigned)(63 - lane);         \
        unsigned P = wave_umax64(max(pk0, pk1));                               \
        int imax = 127 - (int)(P & 127u);                                      \
        float M = unsortable(P & ~127u);                                       \
        float nov = (nact == 0) ? 1.f : fminf(1.f, fmaxf(0.f, 1.f - M * M));   \
        int create = (nov > 0.7f && nact < 100) ? 1 : 0;                       \
        const int idxs = create ? nact : imax;                                 \
        const int cl = idxs & 63, hi = idxs >> 6;                              \
        float dcA = create ? 1.f : 0.95f * d0;                                 \
        float dcB = create ? 1.f : 0.95f * d1;                                 \
        float ccA = create ? trk[k]                                            \
                           : (0.9025f * cn0 + 0.095f * (d0 * r0[k]) +          \
                              0.0025f * trk[k]);                               \
        float ccB = create ? trk[k]                                            \
                           : (0.9025f * cn1 + 0.095f * (d1 * r1[k]) +          \
                              0.0025f * trk[k]);                               \
        float scA = dcA * __builtin_amdgcn_rcpf(__builtin_amdgcn_sqrtf(ccA));  \
        float scB = dcB * __builtin_amdgcn_rcpf(__builtin_amdgcn_sqrtf(ccB));  \
        float ivA = 0.05f * __builtin_amdgcn_rcpf(dcA);                        \
        float ivB = 0.05f * __builtin_amdgcn_rcpf(dcB);                        \
        bool own0 = (lane == cl) && (hi == 0);                                 \
        bool own1 = (lane == cl) && (hi == 1);                                 \
        d0 = own0 ? dcA : d0; cn0 = own0 ? ccA : cn0; s0 = own0 ? scA : s0;    \
        d1 = own1 ? dcB : d1; cn1 = own1 ? ccB : cn1; s1 = own1 ? scB : s1;    \
        float bnew = create ? 1.f : rdlane_f(hi ? ivB : ivA, cl);              \
        nact += create;                                                        \
        float pb0 = own0 ? bnew : 0.f, pb1 = own1 ? bnew : 0.f;                \
        _Pragma("unroll") for (int j = k + 1; j < 8; ++j) {                    \
          r0[j] += pb0 * gxv[k][j];                                            \
          r1[j] += pb1 * gxv[k][j];                                            \
        }                                                                      \
        bnewA[k] = bnew; novA[k] = nov; idxA[k] = idxs;                        \
        _Pragma("unroll") for (int m = 0; m < 4; ++m)                          \
          if (m * 64 + 63 >= c) {                                              \
            const int a_ = idxs * 257 + m * 64 + lane;                         \
            RAW[a_] += bnew * CUR[k][m];                                       \
          }                                                                    \
      }                                                                        \
      if (lane == 0) {                                                         \
        _Pragma("unroll") for (int k = 0; k < 8; ++k) {                        \
          float4 r4; r4.x = bnewA[k]; r4.y = __int_as_float(idxA[k]);          \
          r4.z = novA[k]; r4.w = 0.f;                                          \
          RING[t + k] = r4;                                                    \
        }                                                                      \
        if (((R_) & 7) == 7)                                                   \
          __hip_atomic_store(&FLAG, (R_) + 1, __ATOMIC_RELEASE,                \
                             __HIP_MEMORY_SCOPE_WORKGROUP);                    \
      }                                                                        \
      const int cnx = tn & 255;                                                \
      if (tn < 512 && cnx != 0) {                                              \
        _Pragma("unroll") for (int j = 0; j < 8; ++j)                          \
          r0[j] = RAW[lane * 257 + cnx + j];                                   \
        if (lane < 36) {                                                       \
          _Pragma("unroll") for (int j = 0; j < 8; ++j)                        \
            r1[j] = RAW[(lane + 64) * 257 + cnx + j];                          \
        }                                                                      \
      }                                                                        \
    }

    for (int R = 0; R < 64; R += 2) {
      W0_ROUND(R, bufA, bufB)
      W0_ROUND(R + 1, bufB, bufA)
    }
#undef W0_ROUND
  } else {
    // ================== WAVE 1: lag wave, 8 wake-ups ==================
    float q8[8];
#pragma unroll
    for (int gI = 0; gI < 8; ++gI) q8[gI] = 0.f;
    float n2 = wave_sum64(Kpart[lane]);
    float g = 1.f, ginv = 1.f;

    for (int chunk = 0; chunk < 8; ++chunk) {
      while (__hip_atomic_load(&FLAG, __ATOMIC_ACQUIRE,
                               __HIP_MEMORY_SCOPE_WORKGROUP) < (chunk + 1) * 8)
        __builtin_amdgcn_s_sleep(32);

      for (int r8 = 0; r8 < 8; ++r8) {
        const int R = chunk * 8 + r8;
        const int t = 8 * R;
        float B[8][8];
#pragma unroll
        for (int k = 0; k < 8; ++k)
#pragma unroll
          for (int gI = 0; gI < 8; ++gI)
            B[k][gI] = G[(t + k) * 512 + gI * 64 + lane];

        float4 rgv[8];
#pragma unroll
        for (int k = 0; k < 8; ++k) rgv[k] = RING[t + k];

        float trm[8], gxw[8][8];
#pragma unroll
        for (int m = 0; m < 8; ++m) {
          trm[m] = gx_tbl[(t + m) * 8];
#pragma unroll
          for (int j = m + 1; j < 8; ++j)
            gxw[m][j] = gx_tbl[(t + m) * 8 + (j - m)];
        }
        float4 uuA = *(const float4*)&u_sh[t];
        float4 uuB = *(const float4*)&u_sh[t + 4];
        float um[8] = {uuA.x, uuA.y, uuA.z, uuA.w, uuB.x, uuB.y, uuB.z, uuB.w};

        const int grp = t >> 6;
        float qsel = q8[0];
#pragma unroll
        for (int gI = 1; gI < 8; ++gI) qsel = (grp == gI) ? q8[gI] : qsel;
        float qeff[8];
#pragma unroll
        for (int k = 0; k < 8; ++k) qeff[k] = rdlane_f(qsel, (t & 63) + k);

        float wh[8];
#pragma unroll
        for (int m = 0; m < 8; ++m) {
          float nov = rgv[m].z;
          float iw = nov * __builtin_amdgcn_sqrtf(nov);
          float psc = 384.0f * __builtin_amdgcn_rcpf(fmaxf(trm[m], 1e-8f));
          float ccf = A_BOOSTF * iw * psc;
          float qv = g * (um[m] + qeff[m]);
          float n2n = n2 + 2.f * ccf * qv + ccf * ccf * trm[m] * trm[m];
          float kn = __builtin_amdgcn_sqrtf(n2n);
          float fct = (kn > 50.f) ? 50.f * __builtin_amdgcn_rcpf(kn) : 1.f;
          float fiv = (kn > 50.f) ? kn * 0.02f : 1.f;
          wh[m] = ccf * ginv;
          n2 = n2n * fct * fct; g *= fct; ginv *= fiv;
#pragma unroll
          for (int j = m + 1; j < 8; ++j)
            qeff[j] += wh[m] * gxw[m][j] * gxw[m][j];
        }

        if (lane == 0) {
#pragma unroll
          for (int m = 0; m < 8; ++m) wh_sh[t + m] = wh[m];
        }
#pragma unroll
        for (int gI = 0; gI < 8; ++gI)
#pragma unroll
          for (int k = 0; k < 8; ++k)
            q8[gI] += wh[k] * B[k][gI] * B[k][gI];
      }
    }

    for (int s2 = lane; s2 < 512; s2 += 64) Wout[s2] = wh_sh[s2] * g;
    if (lane == 0) gOut[0] = g;
  }
}

extern "C" void kernel_launch(void* const* d_in, const int* in_sizes, int n_in,
                              void* d_out, int out_size, void* d_ws,
                              size_t ws_size, hipStream_t stream) {
  const float* E = (const float*)d_in[0];   // [512,384]
  const float* K0 = (const float*)d_in[1];  // [384,384]
  float* out = (float*)d_out;               // [512,384]

  float* G = (float*)d_ws;                  // 512*512
  float* M0 = G + 512 * 512;                // 512*384
  float* u = M0 + 512 * 384;                // 512
  float* W = u + 512;                       // 512
  float* gS = W + 512;                      // 1
  float* Kpart = gS + 1;                    // 64

  gemm_nt<<<dim3(16, 16), 256, 0, stream>>>(E, E, G, 512, 384);     // G = E E^T
  gemm_nn<<<dim3(12, 16), 256, 0, stream>>>(E, K0, M0, 384, 384);   // M0 = E K0
  prep_kernel<<<192, 256, 0, stream>>>(E, M0, K0, u, Kpart);
  scan_kernel<<<1, 128, 0, stream>>>(G, u, Kpart, W, gS);
  final_gemm<<<dim3(12, 16), 256, 0, stream>>>(G, E, M0, W, gS, out);
}